// Round 2
// baseline (603.923 us; speedup 1.0000x reference)
//
#include <hip/hip_runtime.h>
#include <hip/hip_bf16.h>

constexpr int NUM = 1000000;
constexpr int DIM = 128;

// Mueller hash with torch/numpy int64 semantics: arithmetic shifts,
// wrapping 64-bit multiply (2nd mul exceeds 2^63 -> wrap via uint64).
__device__ __forceinline__ int bloom_idx(long long t) {
    long long s = t;
    s = (long long)(((unsigned long long)((s >> 16) ^ s)) * 73244475ull);
    s = (long long)(((unsigned long long)((s >> 16) ^ s)) * 73244475ull);
    s = (s >> 16) ^ s;
    long long m = s % (long long)NUM;   // jnp.mod: non-negative result
    if (m < 0) m += NUM;
    return (int)m;
}

// Two tokens per wave. Lanes 0-31 own token 2w, lanes 32-63 own token 2w+1.
// Each lane holds 4 output columns (float4): col = (lane&31)*4.
// Lane computes the hash for probe (lane&7) of ITS token; per probe k the
// half-wave broadcasts lane ((lane&32)|k)'s index via shfl.
// Load phase issues all 8 gathers (each 1 KB: two random 512 B rows) before
// any accumulation -> 8 outstanding vmem ops, 8 KB in flight per wave.
// Store: out[w*256 + lane*4 .. +3] -> one wave-contiguous 1 KB dwordx4 store.
__global__ __launch_bounds__(256) void bloom_embed_kernel(
        const int* __restrict__ t,
        const float* __restrict__ W,
        float* __restrict__ out,
        int n_waves) {
    const int gtid = blockIdx.x * blockDim.x + threadIdx.x;
    const int w    = gtid >> 6;            // wave id -> tokens 2w, 2w+1
    const int lane = threadIdx.x & 63;
    if (w >= n_waves) return;

    const int token = 2 * w + (lane >> 5);
    const long long tv = (long long)t[token];
    const int my_idx = bloom_idx(tv + (long long)(lane & 7));

    const int col = (lane & 31) << 2;      // 4 floats per lane within the row

    // ---- load phase: all 8 probe gathers issued back-to-back ----
    float4 v[8];
#pragma unroll
    for (int k = 0; k < 8; ++k) {
        const int idx = __shfl(my_idx, (lane & 32) | k);   // half-wave bcast
        v[k] = *(const float4*)(W + (size_t)idx * DIM + col);
    }

    // ---- accumulate phase ----
    float4 acc = make_float4(0.f, 0.f, 0.f, 0.f);
#pragma unroll
    for (int k = 0; k < 8; ++k) {
        acc.x += v[k].x; acc.y += v[k].y; acc.z += v[k].z; acc.w += v[k].w;
    }
    acc.x *= 0.125f; acc.y *= 0.125f; acc.z *= 0.125f; acc.w *= 0.125f;

    // tokens 2w,2w+1 are contiguous in out: one 1 KB wave store
    *(float4*)(out + (size_t)w * (2 * DIM) + lane * 4) = acc;
}

extern "C" void kernel_launch(void* const* d_in, const int* in_sizes, int n_in,
                              void* d_out, int out_size, void* d_ws, size_t ws_size,
                              hipStream_t stream) {
    const int*   t = (const int*)d_in[0];     // 65536 tokens
    const float* W = (const float*)d_in[1];   // [1e6, 128] fp32
    float*     out = (float*)d_out;           // [65536, 128] fp32

    const int n_tokens = in_sizes[0];
    const int n_waves  = (n_tokens + 1) / 2;  // 2 tokens per wave
    const int waves_per_block = 256 / 64;
    const int blocks = (n_waves + waves_per_block - 1) / waves_per_block;

    bloom_embed_kernel<<<blocks, 256, 0, stream>>>(t, W, out, n_waves);
}